// Round 9
// baseline (178.847 us; speedup 1.0000x reference)
//
#include <hip/hip_runtime.h>
#include <math.h>

#define NN   100000
#define NE   1600000
#define INC  32
#define HID  64
#define OUTC 40
#define NBUCK 391          // ceil(NN/256) coarse dst-buckets (256 nodes each)
#define BCAP  5120         // slab capacity per bucket (mean 4096, +16 sigma)

typedef short bf16x8 __attribute__((ext_vector_type(8)));
typedef float f32x4  __attribute__((ext_vector_type(4)));
typedef _Float16 f16x2 __attribute__((ext_vector_type(2)));

// bf16 helpers (round-to-nearest-even)
__device__ inline unsigned f2bf(float f) {
    unsigned u = __float_as_uint(f);
    return (u + 0x7fffu + ((u >> 16) & 1u)) >> 16;
}
__device__ inline unsigned packbf(float a, float b) {
    return f2bf(a) | (f2bf(b) << 16);
}
__device__ inline ushort f2h(float f) {
    return __builtin_bit_cast(unsigned short, (_Float16)f);
}
__device__ inline f16x2 u2h(unsigned u) { return __builtin_bit_cast(f16x2, u); }
__device__ inline unsigned h2u(f16x2 h) { return __builtin_bit_cast(unsigned, h); }

// payload decode: src in bits 0-16, p (15-bit fixed) in bits 17-31
__device__ inline int   pdec_s(unsigned v) { return (int)(v & 0x1FFFFu); }
__device__ inline float pdec_p(unsigned v) { return (float)(v >> 17) * (1.0f / 32767.0f); }

// ---------------------------------------------------------------------------
// Binning pass: block-local histogram + one global atomicAdd per bucket per
// block, then run-writes of 8B payloads into per-bucket slabs.
// ---------------------------------------------------------------------------
__global__ __launch_bounds__(256) void k_bin(
    const int* __restrict__ src, const int* __restrict__ dst,
    const float* __restrict__ pseudo,
    int* __restrict__ gcur, uint2* __restrict__ slab)
{
    __shared__ int lh[NBUCK];
    __shared__ int lb[NBUCK];
    int t = threadIdx.x;
    for (int i = t; i < NBUCK; i += 256) lh[i] = 0;
    __syncthreads();

    int base = blockIdx.x * 4096;
#pragma unroll
    for (int i = 0; i < 16; i++) {
        int e = base + i * 256 + t;
        if (e < NE) atomicAdd(&lh[dst[e] >> 8], 1);
    }
    __syncthreads();
    for (int i = t; i < NBUCK; i += 256) {
        int c = lh[i];
        lb[i] = c ? atomicAdd(&gcur[i], c) : 0;
        lh[i] = 0;
    }
    __syncthreads();
#pragma unroll
    for (int i = 0; i < 16; i++) {
        int e = base + i * 256 + t;
        if (e < NE) {
            int d = dst[e];
            int b = d >> 8;
            int loc = atomicAdd(&lh[b], 1);
            unsigned pq = (unsigned)__float2int_rn(pseudo[e] * 32767.0f);
            slab[(size_t)b * BCAP + lb[b] + loc] =
                make_uint2((unsigned)src[e] | (pq << 17), (unsigned)(d & 255));
        }
    }
}

// exclusive scan of bucket sizes (one block)
__global__ __launch_bounds__(512) void k_bscan(const int* __restrict__ gcur,
                                               int* __restrict__ bbase)
{
    __shared__ int tmp[512];
    int t = threadIdx.x;
    int v = (t < NBUCK) ? gcur[t] : 0;
    tmp[t] = v;
    __syncthreads();
    for (int off = 1; off < 512; off <<= 1) {
        int add = (t >= off) ? tmp[t - off] : 0;
        __syncthreads();
        tmp[t] += add;
        __syncthreads();
    }
    if (t < NBUCK) bbase[t] = tmp[t] - v;
}

// Per-bucket CSR finalize: counts, offsets, and dst-ordered 4B payloads.
__global__ __launch_bounds__(256) void k_csr(
    const uint2* __restrict__ slab, const int* __restrict__ gcur,
    const int* __restrict__ bbase,
    int* __restrict__ cnt, int* __restrict__ offs, unsigned* __restrict__ pay)
{
    __shared__ int cl[256], ol[256], cur[256];
    __shared__ int ssz, sbase;
    int b = blockIdx.x, t = threadIdx.x;
    if (t == 0) { ssz = gcur[b]; sbase = bbase[b]; }
    cl[t] = 0;
    __syncthreads();
    int sz = ssz, base0 = sbase;
    const uint2* sl = slab + (size_t)b * BCAP;

    for (int i = t; i < sz; i += 256) atomicAdd(&cl[sl[i].y], 1);
    __syncthreads();

    int v = cl[t];
    ol[t] = v;
    __syncthreads();
    for (int off = 1; off < 256; off <<= 1) {
        int add = (t >= off) ? ol[t - off] : 0;
        __syncthreads();
        ol[t] += add;
        __syncthreads();
    }
    int excl = ol[t] - v;
    __syncthreads();
    ol[t] = excl;
    cur[t] = 0;
    int node = b * 256 + t;
    if (node < NN) { cnt[node] = v; offs[node] = base0 + excl; }
    __syncthreads();

    for (int i = t; i < sz; i += 256) {
        uint2 v2 = sl[i];
        int loc = atomicAdd(&cur[v2.y], 1);
        pay[base0 + ol[v2.y] + loc] = v2.x;
    }
}

// ---------------------------------------------------------------------------
// x -> fp16 packed rows ((NN+1) rows; row NN = zeros for invalid-lane gathers)
// ---------------------------------------------------------------------------
__global__ __launch_bounds__(256) void k_xh(const float* __restrict__ x,
                                            unsigned* __restrict__ xh)
{
    int i = blockIdx.x * 256 + threadIdx.x;
    if (i >= (NN + 1) * 16) return;
    unsigned r = 0;
    if (i < NN * 16) {
        float2 v = ((const float2*)x)[i];
        r = (unsigned)f2h(v.x) | ((unsigned)f2h(v.y) << 16);
    }
    xh[i] = r;
}

// ---------------------------------------------------------------------------
// Weight prep (bf16 MFMA operands):
//  W1T[64][96]: k<32 -> W1[0]; 32<=k<64 -> W1[1]-W1[0]; k>=64 -> root1 (^T)
//  W2T[128][64]: col j<80: m=j>>3,q=j&7,o=4m+(q&3); q<4 -> W2[0][:,o],
//                q>=4 -> W2[1][:,o]-W2[0][:,o]; 80..119: root2; 120..127: 0
// ---------------------------------------------------------------------------
__global__ __launch_bounds__(256) void k_wprep(
    const float* __restrict__ W1, const float* __restrict__ root1,
    const float* __restrict__ W2, const float* __restrict__ root2,
    ushort* __restrict__ W1T, ushort* __restrict__ W2T)
{
    int i = blockIdx.x * 256 + threadIdx.x;
    if (i < 64 * 96) {
        int o = i / 96, k = i % 96;
        float v;
        if (k < 32)      v = W1[k * HID + o];
        else if (k < 64) v = W1[INC * HID + (k - 32) * HID + o] - W1[(k - 32) * HID + o];
        else             v = root1[(k - 64) * HID + o];
        W1T[i] = (ushort)f2bf(v);
    }
    int i2 = i - 64 * 96;
    if (i2 >= 0 && i2 < 128 * 64) {
        int j = i2 / 64, k = i2 % 64;
        float v = 0.0f;
        if (j < 80) {
            int o = (j >> 3) * 4 + (j & 3);
            float g0 = W2[k * OUTC + o];
            v = ((j & 7) < 4) ? g0 : (W2[HID * OUTC + k * OUTC + o] - g0);
        } else if (j < 120) {
            v = root2[k * OUTC + (j - 80)];
        }
        W2T[i2] = (ushort)f2bf(v);
    }
}

// ---------------------------------------------------------------------------
// Layer 1 gather: wave per node, 8 edges per vmem instruction, packed-f16
// accumulate of S=sum(x) and T=sum(p*x). Apre = [S*inv | T*inv | x] (bf16).
// ---------------------------------------------------------------------------
__global__ __launch_bounds__(256) void k_agg1(
    const unsigned* __restrict__ xh, const unsigned* __restrict__ pay,
    const int* __restrict__ offs, const int* __restrict__ cnt,
    ushort* __restrict__ Apre)
{
    int t = threadIdx.x;
    int w = t >> 6, lane = t & 63;
    int slot = lane >> 3, sub = lane & 7;

    for (int n0 = blockIdx.x * 4; n0 < NN; n0 += gridDim.x * 4) {
        int n = n0 + w;
        int e0 = offs[n], c = cnt[n];

        f16x2 S0 = {}, S1 = {}, T0 = {}, T1 = {};

        for (int base = 0; base < c; base += 64) {
            int bc = min(c - base, 64);
            int li = (lane < bc) ? lane : (bc - 1);
            unsigned pl = pay[e0 + base + li];
            for (int g = 0; g < bc; g += 8) {
                int je = g + slot;                       // <= 63
                unsigned v = (unsigned)__shfl((int)pl, je);
                int sj = (je < bc) ? pdec_s(v) : NN;     // invalid -> zero row
                _Float16 ph = (_Float16)pdec_p(v);
                f16x2 pp = {ph, ph};
                uint2 gv = *((const uint2*)(xh + (size_t)sj * 16) + sub);
                f16x2 v0 = u2h(gv.x), v1 = u2h(gv.y);
                S0 += v0; S1 += v1;
                T0 = __builtin_elementwise_fma(pp, v0, T0);
                T1 = __builtin_elementwise_fma(pp, v1, T1);
            }
        }

        // butterfly over 8 slots on packed values
#pragma unroll
        for (int mask = 8; mask <= 32; mask <<= 1) {
            S0 += u2h((unsigned)__shfl_xor((int)h2u(S0), mask));
            S1 += u2h((unsigned)__shfl_xor((int)h2u(S1), mask));
            T0 += u2h((unsigned)__shfl_xor((int)h2u(T0), mask));
            T1 += u2h((unsigned)__shfl_xor((int)h2u(T1), mask));
        }
        if (slot == 0) {
            float inv = 1.0f / fmaxf((float)c, 1.0f);
            ushort* ap = Apre + (size_t)n * 96;
            *(uint2*)(ap + sub * 4) = make_uint2(
                packbf((float)S0[0] * inv, (float)S0[1] * inv),
                packbf((float)S1[0] * inv, (float)S1[1] * inv));
            *(uint2*)(ap + 32 + sub * 4) = make_uint2(
                packbf((float)T0[0] * inv, (float)T0[1] * inv),
                packbf((float)T1[0] * inv, (float)T1[1] * inv));
            uint2 xv = *((const uint2*)(xh + (size_t)n * 16) + sub);
            f16x2 x0 = u2h(xv.x), x1 = u2h(xv.y);
            *(uint2*)(ap + 64 + sub * 4) = make_uint2(
                packbf((float)x0[0], (float)x0[1]),
                packbf((float)x1[0], (float)x1[1]));
        }
    }
}

// ---------------------------------------------------------------------------
// Node transform on MFMA: 64 nodes/block, 4 waves x 16-node M-tiles.
// GEMM1 -> h (bf16 LDS); GEMM2 -> hw2f (fp16 [g0x4|dx4] groups) + rt (f32).
// ---------------------------------------------------------------------------
__global__ __launch_bounds__(256) void k_node_mfma(
    const ushort* __restrict__ Apre, const ushort* __restrict__ W1T,
    const ushort* __restrict__ W2T, const float* __restrict__ b1,
    const float* __restrict__ b2,
    ushort* __restrict__ hw2f_us, float* __restrict__ rt)
{
    __shared__ ushort sA[64 * 104];
    __shared__ ushort sW1[64 * 104];
    __shared__ ushort sW2[128 * 72];
    __shared__ ushort sH[4 * 16 * 72];
    __shared__ float sb1[HID], sb2[OUTC];

    int t = threadIdx.x;
    int nbase = blockIdx.x * 64;

#pragma unroll
    for (int i = 0; i < 3; i++) {
        int idx = t + i * 256;
        int row = idx / 12, c = idx % 12;
        uint4 v = make_uint4(0, 0, 0, 0);
        if (nbase + row < NN)
            v = *(const uint4*)(Apre + (size_t)(nbase + row) * 96 + c * 8);
        *(uint4*)(sA + row * 104 + c * 8) = v;
    }
#pragma unroll
    for (int i = 0; i < 3; i++) {
        int idx = t + i * 256;
        int row = idx / 12, c = idx % 12;
        *(uint4*)(sW1 + row * 104 + c * 8) =
            *(const uint4*)(W1T + row * 96 + c * 8);
    }
#pragma unroll
    for (int i = 0; i < 4; i++) {
        int idx = t + i * 256;
        int row = idx / 8, c = idx % 8;
        *(uint4*)(sW2 + row * 72 + c * 8) =
            *(const uint4*)(W2T + row * 64 + c * 8);
    }
    if (t < HID) sb1[t] = b1[t];
    if (t >= 64 && t < 64 + OUTC) sb2[t - 64] = b2[t - 64];
    __syncthreads();

    int w = t >> 6, lane = t & 63;
    int lm = lane & 15, lk = lane >> 4;

    f32x4 acc[4];
#pragma unroll
    for (int nt = 0; nt < 4; nt++) acc[nt] = (f32x4){0.f, 0.f, 0.f, 0.f};
#pragma unroll
    for (int kk = 0; kk < 3; kk++) {
        bf16x8 af = *(const bf16x8*)(sA + (w * 16 + lm) * 104 + kk * 32 + lk * 8);
#pragma unroll
        for (int nt = 0; nt < 4; nt++) {
            bf16x8 bfr = *(const bf16x8*)(sW1 + (nt * 16 + lm) * 104 + kk * 32 + lk * 8);
            acc[nt] = __builtin_amdgcn_mfma_f32_16x16x32_bf16(af, bfr, acc[nt], 0, 0, 0);
        }
    }

    ushort* hrow = sH + w * 16 * 72;
#pragma unroll
    for (int nt = 0; nt < 4; nt++) {
#pragma unroll
        for (int r = 0; r < 4; r++) {
            float v = acc[nt][r] + sb1[nt * 16 + lm];
            v = (v > 0.0f) ? v : (expf(v) - 1.0f);
            hrow[(lk * 4 + r) * 72 + nt * 16 + lm] = (ushort)f2bf(v);
        }
    }
    asm volatile("" ::: "memory");

    f32x4 g[8];
#pragma unroll
    for (int nt = 0; nt < 8; nt++) g[nt] = (f32x4){0.f, 0.f, 0.f, 0.f};
#pragma unroll
    for (int kk = 0; kk < 2; kk++) {
        bf16x8 af = *(const bf16x8*)(hrow + lm * 72 + kk * 32 + lk * 8);
#pragma unroll
        for (int nt = 0; nt < 8; nt++) {
            bf16x8 bfr = *(const bf16x8*)(sW2 + (nt * 16 + lm) * 72 + kk * 32 + lk * 8);
            g[nt] = __builtin_amdgcn_mfma_f32_16x16x32_bf16(af, bfr, g[nt], 0, 0, 0);
        }
    }

#pragma unroll
    for (int nt = 0; nt < 8; nt++) {
        int j = nt * 16 + lm;
#pragma unroll
        for (int r = 0; r < 4; r++) {
            int node = nbase + w * 16 + lk * 4 + r;
            if (node >= NN) continue;
            float v = g[nt][r];
            if (j < 80)
                hw2f_us[(size_t)node * 80 + j] = f2h(v);
            else if (j < 120)
                rt[(size_t)node * 40 + (j - 80)] = v + sb2[j - 80];
        }
    }
}

// ---------------------------------------------------------------------------
// Layer 2: wave per node, 6 edges per vmem instruction (10 lanes x uint4 =
// [g0 x4 | d x4] fp16). msg = g0 + p*d via 2 pk_fma + 2 pk_add per edge-lane.
// ---------------------------------------------------------------------------
__global__ __launch_bounds__(256) void k_agg2f(
    const unsigned* __restrict__ hw2f, const float* __restrict__ rt,
    const unsigned* __restrict__ pay, const int* __restrict__ offs,
    const int* __restrict__ cnt, float* __restrict__ out)
{
    __shared__ float scr[4][OUTC];
    int t = threadIdx.x;
    int w = t >> 6, lane = t & 63;
    int slot = lane / 10;            // 0..5 active, 6 = lanes 60-63 (zero row)
    int m = lane - slot * 10;        // 0..9 -> outputs 4m..4m+3

    for (int n0 = blockIdx.x * 4; n0 < NN; n0 += gridDim.x * 4) {
        int n = n0 + w;
        int e0 = offs[n], c = cnt[n];

        f16x2 Aa = {}, Ab = {};
        for (int base = 0; base < c; base += 64) {
            int bc = min(c - base, 64);
            int li = (lane < bc) ? lane : (bc - 1);
            unsigned pl = pay[e0 + base + li];
            for (int g = 0; g < bc; g += 6) {
                int je = g + slot;
                unsigned v = (unsigned)__shfl((int)pl, je & 63);
                bool valid = (slot < 6) && (je < bc);
                int sj = valid ? pdec_s(v) : NN;        // invalid -> zero row
                _Float16 ph = (_Float16)pdec_p(v);
                f16x2 pp = {ph, ph};
                uint4 gv = *((const uint4*)(hw2f + (size_t)sj * 40) + m);
                Aa += __builtin_elementwise_fma(pp, u2h(gv.z), u2h(gv.x));
                Ab += __builtin_elementwise_fma(pp, u2h(gv.w), u2h(gv.y));
            }
        }

        // fold 6 slots (packed): +30, then +10 and +20
        Aa += u2h((unsigned)__shfl((int)h2u(Aa), (lane + 30) & 63));
        Ab += u2h((unsigned)__shfl((int)h2u(Ab), (lane + 30) & 63));
        {
            unsigned ua = h2u(Aa), ub = h2u(Ab);
            Aa += u2h((unsigned)__shfl((int)ua, (lane + 10) & 63))
                + u2h((unsigned)__shfl((int)ua, (lane + 20) & 63));
            Ab += u2h((unsigned)__shfl((int)ub, (lane + 10) & 63))
                + u2h((unsigned)__shfl((int)ub, (lane + 20) & 63));
        }

        asm volatile("" ::: "memory");
        if (lane < 10) {
            scr[w][4 * m]     = (float)Aa[0];
            scr[w][4 * m + 1] = (float)Aa[1];
            scr[w][4 * m + 2] = (float)Ab[0];
            scr[w][4 * m + 3] = (float)Ab[1];
        }
        asm volatile("" ::: "memory");

        float inv = 1.0f / fmaxf((float)c, 1.0f);
        float r = 0.0f;
        if (lane < OUTC)
            r = fmaf(scr[w][lane], inv, rt[(size_t)n * OUTC + lane]);

        float mx = (lane < OUTC) ? r : -1e30f;
#pragma unroll
        for (int off = 32; off > 0; off >>= 1) mx = fmaxf(mx, __shfl_xor(mx, off));
        float ex = (lane < OUTC) ? expf(r - mx) : 0.0f;
#pragma unroll
        for (int off = 32; off > 0; off >>= 1) ex += __shfl_xor(ex, off);
        float lse = mx + logf(ex);

        if (lane < OUTC) out[(size_t)n * OUTC + lane] = r - lse;
    }
}

// ---------------------------------------------------------------------------
extern "C" void kernel_launch(void* const* d_in, const int* in_sizes, int n_in,
                              void* d_out, int out_size, void* d_ws, size_t ws_size,
                              hipStream_t stream)
{
    const float* x     = (const float*)d_in[0];
    const int*   ei    = (const int*)  d_in[1];
    const float* ea    = (const float*)d_in[2];
    const float* W1    = (const float*)d_in[3];
    const float* root1 = (const float*)d_in[4];
    const float* b1    = (const float*)d_in[5];
    const float* W2    = (const float*)d_in[6];
    const float* root2 = (const float*)d_in[7];
    const float* b2    = (const float*)d_in[8];
    float* out = (float*)d_out;

    const int* src = ei;
    const int* dst = ei + NE;

    // workspace layout (~81.6 MB)
    char* wsp = (char*)d_ws;
    int*  cnt   = (int*)wsp;  wsp += sizeof(int) * NN;
    int*  offs  = (int*)wsp;  wsp += sizeof(int) * NN;
    int*  gcur  = (int*)wsp;  wsp += sizeof(int) * 512;
    int*  bbase = (int*)wsp;  wsp += sizeof(int) * 512;
    unsigned* pay = (unsigned*)wsp; wsp += sizeof(unsigned) * NE;                     // 6.4 MB
    unsigned* xh  = (unsigned*)wsp; wsp += sizeof(unsigned) * (size_t)(NN + 1) * 16;  // 6.4 MB
    ushort* Apre  = (ushort*)wsp; wsp += sizeof(ushort) * (size_t)NN * 96;            // 19.2 MB
    ushort* hw2f  = (ushort*)wsp; wsp += sizeof(ushort) * (size_t)(NN + 1) * 80;      // 16 MB
    float* rt     = (float*)wsp; wsp += sizeof(float) * (size_t)NN * OUTC;            // 16 MB
    ushort* W1T   = (ushort*)wsp; wsp += sizeof(ushort) * 64 * 96;
    ushort* W2T   = (ushort*)wsp; wsp += sizeof(ushort) * 128 * 64;
    wsp = (char*)(((size_t)wsp + 15) & ~(size_t)15);
    uint2* slab   = (uint2*)wsp; wsp += sizeof(uint2) * (size_t)NBUCK * BCAP;         // 16 MB

    hipMemsetAsync(gcur, 0, sizeof(int) * 512, stream);
    hipMemsetAsync((char*)hw2f + (size_t)NN * 160, 0, 160, stream);  // zero row

    k_xh    <<<((NN + 1) * 16 + 255) / 256, 256, 0, stream>>>(x, xh);
    k_wprep <<<(64 * 96 + 128 * 64 + 255) / 256, 256, 0, stream>>>(W1, root1, W2, root2, W1T, W2T);
    k_bin   <<<(NE + 4095) / 4096, 256, 0, stream>>>(src, dst, ea, gcur, slab);
    k_bscan <<<1, 512, 0, stream>>>(gcur, bbase);
    k_csr   <<<NBUCK, 256, 0, stream>>>(slab, gcur, bbase, cnt, offs, pay);

    k_agg1  <<<2048, 256, 0, stream>>>(xh, pay, offs, cnt, Apre);
    k_node_mfma<<<(NN + 63) / 64, 256, 0, stream>>>(Apre, W1T, W2T, b1, b2, hw2f, rt);
    k_agg2f <<<2048, 256, 0, stream>>>((const unsigned*)hw2f, rt, pay, offs, cnt, out);
}

// Round 10
// 172.562 us; speedup vs baseline: 1.0364x; 1.0364x over previous
//
#include <hip/hip_runtime.h>
#include <math.h>

#define NN   100000
#define NE   1600000
#define INC  32
#define HID  64
#define OUTC 40
#define NBUCK 391          // ceil(NN/256) coarse dst-buckets (256 nodes each)
#define BCAP  5120         // slab capacity per bucket (mean 4096, +16 sigma)

typedef short bf16x8 __attribute__((ext_vector_type(8)));
typedef float f32x4  __attribute__((ext_vector_type(4)));
typedef float v2f    __attribute__((ext_vector_type(2)));

// bf16 helpers (round-to-nearest-even)
__device__ inline unsigned f2bf(float f) {
    unsigned u = __float_as_uint(f);
    return (u + 0x7fffu + ((u >> 16) & 1u)) >> 16;
}
__device__ inline unsigned packbf(float a, float b) {
    return f2bf(a) | (f2bf(b) << 16);
}

// payload decode: src in bits 0-16, p (15-bit fixed) in bits 17-31
__device__ inline int   pdec_s(unsigned v) { return (int)(v & 0x1FFFFu); }
__device__ inline float pdec_p(unsigned v) { return (float)(v >> 17) * (1.0f / 32767.0f); }

// ---------------------------------------------------------------------------
// Binning pass: block-local histogram + one global atomicAdd per bucket per
// block, then run-writes of 8B payloads into per-bucket slabs.
// ---------------------------------------------------------------------------
__global__ __launch_bounds__(256) void k_bin(
    const int* __restrict__ src, const int* __restrict__ dst,
    const float* __restrict__ pseudo,
    int* __restrict__ gcur, uint2* __restrict__ slab)
{
    __shared__ int lh[NBUCK];
    __shared__ int lb[NBUCK];
    int t = threadIdx.x;
    for (int i = t; i < NBUCK; i += 256) lh[i] = 0;
    __syncthreads();

    int base = blockIdx.x * 4096;
#pragma unroll
    for (int i = 0; i < 16; i++) {
        int e = base + i * 256 + t;
        if (e < NE) atomicAdd(&lh[dst[e] >> 8], 1);
    }
    __syncthreads();
    for (int i = t; i < NBUCK; i += 256) {
        int c = lh[i];
        lb[i] = c ? atomicAdd(&gcur[i], c) : 0;
        lh[i] = 0;
    }
    __syncthreads();
#pragma unroll
    for (int i = 0; i < 16; i++) {
        int e = base + i * 256 + t;
        if (e < NE) {
            int d = dst[e];
            int b = d >> 8;
            int loc = atomicAdd(&lh[b], 1);
            unsigned pq = (unsigned)__float2int_rn(pseudo[e] * 32767.0f);
            slab[(size_t)b * BCAP + lb[b] + loc] =
                make_uint2((unsigned)src[e] | (pq << 17), (unsigned)(d & 255));
        }
    }
}

// exclusive scan of bucket sizes (one block)
__global__ __launch_bounds__(512) void k_bscan(const int* __restrict__ gcur,
                                               int* __restrict__ bbase)
{
    __shared__ int tmp[512];
    int t = threadIdx.x;
    int v = (t < NBUCK) ? gcur[t] : 0;
    tmp[t] = v;
    __syncthreads();
    for (int off = 1; off < 512; off <<= 1) {
        int add = (t >= off) ? tmp[t - off] : 0;
        __syncthreads();
        tmp[t] += add;
        __syncthreads();
    }
    if (t < NBUCK) bbase[t] = tmp[t] - v;
}

// Per-bucket CSR finalize: counts, offsets, and dst-ordered 4B payloads.
__global__ __launch_bounds__(256) void k_csr(
    const uint2* __restrict__ slab, const int* __restrict__ gcur,
    const int* __restrict__ bbase,
    int* __restrict__ cnt, int* __restrict__ offs, unsigned* __restrict__ pay)
{
    __shared__ int cl[256], ol[256], cur[256];
    __shared__ int ssz, sbase;
    int b = blockIdx.x, t = threadIdx.x;
    if (t == 0) { ssz = gcur[b]; sbase = bbase[b]; }
    cl[t] = 0;
    __syncthreads();
    int sz = ssz, base0 = sbase;
    const uint2* sl = slab + (size_t)b * BCAP;

    for (int i = t; i < sz; i += 256) atomicAdd(&cl[sl[i].y], 1);
    __syncthreads();

    int v = cl[t];
    ol[t] = v;
    __syncthreads();
    for (int off = 1; off < 256; off <<= 1) {
        int add = (t >= off) ? ol[t - off] : 0;
        __syncthreads();
        ol[t] += add;
        __syncthreads();
    }
    int excl = ol[t] - v;
    __syncthreads();
    ol[t] = excl;
    cur[t] = 0;
    int node = b * 256 + t;
    if (node < NN) { cnt[node] = v; offs[node] = base0 + excl; }
    __syncthreads();

    for (int i = t; i < sz; i += 256) {
        uint2 v2 = sl[i];
        int loc = atomicAdd(&cur[v2.y], 1);
        pay[base0 + ol[v2.y] + loc] = v2.x;
    }
}

// ---------------------------------------------------------------------------
// x -> fp8(e4m3) packed rows, 32 B/row; row NN = zeros (invalid-lane target)
// ---------------------------------------------------------------------------
__global__ __launch_bounds__(256) void k_xq(const float* __restrict__ x,
                                            unsigned* __restrict__ xq)
{
    int i = blockIdx.x * 256 + threadIdx.x;
    if (i >= (NN + 1) * 8) return;
    unsigned u = 0;
    if (i < NN * 8) {
        float4 v = ((const float4*)x)[i];
        u = __builtin_amdgcn_cvt_pk_fp8_f32(v.x, v.y, 0, false);
        u = __builtin_amdgcn_cvt_pk_fp8_f32(v.z, v.w, u, true);
    }
    xq[i] = u;
}

// ---------------------------------------------------------------------------
// Weight prep (bf16 MFMA operands):
//  W1T[64][96]: k<32 -> W1[0]; 32<=k<64 -> W1[1]-W1[0]; k>=64 -> root1 (^T)
//  W2T[128][64]: col j<80: o=(j>>3)*4+(j&3); (j&7)<4 -> W2[0][:,o],
//                else W2[1][:,o]-W2[0][:,o]; 80..119: root2; 120..127: 0
// ---------------------------------------------------------------------------
__global__ __launch_bounds__(256) void k_wprep(
    const float* __restrict__ W1, const float* __restrict__ root1,
    const float* __restrict__ W2, const float* __restrict__ root2,
    ushort* __restrict__ W1T, ushort* __restrict__ W2T)
{
    int i = blockIdx.x * 256 + threadIdx.x;
    if (i < 64 * 96) {
        int o = i / 96, k = i % 96;
        float v;
        if (k < 32)      v = W1[k * HID + o];
        else if (k < 64) v = W1[INC * HID + (k - 32) * HID + o] - W1[(k - 32) * HID + o];
        else             v = root1[(k - 64) * HID + o];
        W1T[i] = (ushort)f2bf(v);
    }
    int i2 = i - 64 * 96;
    if (i2 >= 0 && i2 < 128 * 64) {
        int j = i2 / 64, k = i2 % 64;
        float v = 0.0f;
        if (j < 80) {
            int o = (j >> 3) * 4 + (j & 3);
            float g0 = W2[k * OUTC + o];
            v = ((j & 7) < 4) ? g0 : (W2[HID * OUTC + k * OUTC + o] - g0);
        } else if (j < 120) {
            v = root2[k * OUTC + (j - 80)];
        }
        W2T[i2] = (ushort)f2bf(v);
    }
}

// ---------------------------------------------------------------------------
// Layer 1 gather: wave per node, 8 edges per vmem instruction; lane reads one
// dword = 4 fp8 feats. S=sum(x), T=sum(p*x) in packed f32.
// Apre = [S*inv | T*inv | x(f32 source)] (bf16).
// ---------------------------------------------------------------------------
__global__ __launch_bounds__(256) void k_agg1(
    const unsigned* __restrict__ xq, const unsigned* __restrict__ pay,
    const int* __restrict__ offs, const int* __restrict__ cnt,
    const float* __restrict__ x, ushort* __restrict__ Apre)
{
    int t = threadIdx.x;
    int w = t >> 6, lane = t & 63;
    int slot = lane >> 3, sub = lane & 7;

    for (int n0 = blockIdx.x * 4; n0 < NN; n0 += gridDim.x * 4) {
        int n = n0 + w;
        int e0 = offs[n], c = cnt[n];

        v2f S01 = {0.f, 0.f}, S23 = {0.f, 0.f};
        v2f T01 = {0.f, 0.f}, T23 = {0.f, 0.f};

        for (int base = 0; base < c; base += 64) {
            int bc = min(c - base, 64);
            int li = (lane < bc) ? lane : (bc - 1);
            unsigned pl = pay[e0 + base + li];
            for (int g = 0; g < bc; g += 8) {
                int je = g + slot;                       // <= 63
                unsigned v = (unsigned)__shfl((int)pl, je);
                int sj = (je < bc) ? pdec_s(v) : NN;     // invalid -> zero row
                float pj = pdec_p(v);
                v2f pp = {pj, pj};
                unsigned gv = xq[sj * 8 + sub];
                v2f v01 = __builtin_amdgcn_cvt_pk_f32_fp8(gv, false);
                v2f v23 = __builtin_amdgcn_cvt_pk_f32_fp8(gv, true);
                S01 += v01; S23 += v23;
                T01 = __builtin_elementwise_fma(pp, v01, T01);
                T23 = __builtin_elementwise_fma(pp, v23, T23);
            }
        }

        // butterfly over 8 slots (lane bits 3..5)
#pragma unroll
        for (int mask = 8; mask <= 32; mask <<= 1) {
            S01.x += __shfl_xor(S01.x, mask); S01.y += __shfl_xor(S01.y, mask);
            S23.x += __shfl_xor(S23.x, mask); S23.y += __shfl_xor(S23.y, mask);
            T01.x += __shfl_xor(T01.x, mask); T01.y += __shfl_xor(T01.y, mask);
            T23.x += __shfl_xor(T23.x, mask); T23.y += __shfl_xor(T23.y, mask);
        }
        if (slot == 0) {
            float inv = 1.0f / fmaxf((float)c, 1.0f);
            ushort* ap = Apre + (size_t)n * 96;
            *(uint2*)(ap + sub * 4) = make_uint2(
                packbf(S01.x * inv, S01.y * inv), packbf(S23.x * inv, S23.y * inv));
            *(uint2*)(ap + 32 + sub * 4) = make_uint2(
                packbf(T01.x * inv, T01.y * inv), packbf(T23.x * inv, T23.y * inv));
            float4 xv = *((const float4*)(x + (size_t)n * INC) + sub);
            *(uint2*)(ap + 64 + sub * 4) = make_uint2(
                packbf(xv.x, xv.y), packbf(xv.z, xv.w));
        }
    }
}

// ---------------------------------------------------------------------------
// Node transform on MFMA: 64 nodes/block, 4 waves x 16-node M-tiles.
// GEMM1 -> h (bf16 LDS); GEMM2 -> hwq (fp8 interleaved [g0-quad|d-quad] per
// uint pair, 80 B/row, repacked via LDS staging) + rt (f32, +b2).
// ---------------------------------------------------------------------------
__global__ __launch_bounds__(256) void k_node_mfma(
    const ushort* __restrict__ Apre, const ushort* __restrict__ W1T,
    const ushort* __restrict__ W2T, const float* __restrict__ b1,
    const float* __restrict__ b2,
    unsigned* __restrict__ hwq, float* __restrict__ rt)
{
    // unified LDS: sA[64*104] | sW1[64*104] | sW2[128*72] | sH[4*16*72]
    __shared__ __align__(16) ushort smem[27136];
    __shared__ float sb1[HID], sb2[OUTC];
    ushort* sA  = smem;
    ushort* sW1 = smem + 6656;
    ushort* sW2 = smem + 13312;
    ushort* sH  = smem + 22528;
    float*  sGf = (float*)smem;          // 64*80 f32 = 20480 B, aliases sA+sW1

    int t = threadIdx.x;
    int nbase = blockIdx.x * 64;

#pragma unroll
    for (int i = 0; i < 3; i++) {
        int idx = t + i * 256;
        int row = idx / 12, c = idx % 12;
        uint4 v = make_uint4(0, 0, 0, 0);
        if (nbase + row < NN)
            v = *(const uint4*)(Apre + (size_t)(nbase + row) * 96 + c * 8);
        *(uint4*)(sA + row * 104 + c * 8) = v;
    }
#pragma unroll
    for (int i = 0; i < 3; i++) {
        int idx = t + i * 256;
        int row = idx / 12, c = idx % 12;
        *(uint4*)(sW1 + row * 104 + c * 8) =
            *(const uint4*)(W1T + row * 96 + c * 8);
    }
#pragma unroll
    for (int i = 0; i < 4; i++) {
        int idx = t + i * 256;
        int row = idx / 8, c = idx % 8;
        *(uint4*)(sW2 + row * 72 + c * 8) =
            *(const uint4*)(W2T + row * 64 + c * 8);
    }
    if (t < HID) sb1[t] = b1[t];
    if (t >= 64 && t < 64 + OUTC) sb2[t - 64] = b2[t - 64];
    __syncthreads();

    int w = t >> 6, lane = t & 63;
    int lm = lane & 15, lk = lane >> 4;

    // GEMM1: nodes [w*16, w*16+16), K=96
    f32x4 acc[4];
#pragma unroll
    for (int nt = 0; nt < 4; nt++) acc[nt] = (f32x4){0.f, 0.f, 0.f, 0.f};
#pragma unroll
    for (int kk = 0; kk < 3; kk++) {
        bf16x8 af = *(const bf16x8*)(sA + (w * 16 + lm) * 104 + kk * 32 + lk * 8);
#pragma unroll
        for (int nt = 0; nt < 4; nt++) {
            bf16x8 bfr = *(const bf16x8*)(sW1 + (nt * 16 + lm) * 104 + kk * 32 + lk * 8);
            acc[nt] = __builtin_amdgcn_mfma_f32_16x16x32_bf16(af, bfr, acc[nt], 0, 0, 0);
        }
    }

    // epilogue 1: +b1, ELU, write h tile (wave-local)
    ushort* hrow = sH + w * 16 * 72;
#pragma unroll
    for (int nt = 0; nt < 4; nt++) {
#pragma unroll
        for (int r = 0; r < 4; r++) {
            float v = acc[nt][r] + sb1[nt * 16 + lm];
            v = (v > 0.0f) ? v : (expf(v) - 1.0f);
            hrow[(lk * 4 + r) * 72 + nt * 16 + lm] = (ushort)f2bf(v);
        }
    }
    __syncthreads();   // all GEMM1 reads of sA/sW1 done before sGf aliasing

    // GEMM2: h[16x64] @ W2T^T -> 16 x 128, K=64
    f32x4 g[8];
#pragma unroll
    for (int nt = 0; nt < 8; nt++) g[nt] = (f32x4){0.f, 0.f, 0.f, 0.f};
#pragma unroll
    for (int kk = 0; kk < 2; kk++) {
        bf16x8 af = *(const bf16x8*)(hrow + lm * 72 + kk * 32 + lk * 8);
#pragma unroll
        for (int nt = 0; nt < 8; nt++) {
            bf16x8 bfr = *(const bf16x8*)(sW2 + (nt * 16 + lm) * 72 + kk * 32 + lk * 8);
            g[nt] = __builtin_amdgcn_mfma_f32_16x16x32_bf16(af, bfr, g[nt], 0, 0, 0);
        }
    }

    // epilogue 2: stage g0/d into sGf[nl][80] (g0 at 0..39, d at 40..79);
    // rt (j 80..119) written directly.
#pragma unroll
    for (int nt = 0; nt < 8; nt++) {
        int j = nt * 16 + lm;
        int o = (j >> 3) * 4 + (j & 3);
        int s = ((j & 7) < 4) ? o : (40 + o);
#pragma unroll
        for (int r = 0; r < 4; r++) {
            int nl = w * 16 + lk * 4 + r;
            float v = g[nt][r];
            if (j < 80) {
                sGf[nl * 80 + s] = v;
            } else if (j < 120) {
                int node = nbase + nl;
                if (node < NN) rt[(size_t)node * 40 + (j - 80)] = v + sb2[j - 80];
            }
        }
    }
    __syncthreads();

    // repack: uint k of row: quad q=k>>1, isd=k&1 -> values s0=isd*40+4q
    for (int idx = t; idx < 64 * 20; idx += 256) {
        int nl = idx / 20, k = idx % 20;
        int node = nbase + nl;
        if (node < NN) {
            int s0 = (k & 1) * 40 + (k >> 1) * 4;
            const float* gp = sGf + nl * 80 + s0;
            unsigned u = __builtin_amdgcn_cvt_pk_fp8_f32(gp[0], gp[1], 0, false);
            u = __builtin_amdgcn_cvt_pk_fp8_f32(gp[2], gp[3], u, true);
            hwq[(size_t)node * 20 + k] = u;
        }
    }
}

// ---------------------------------------------------------------------------
// Layer 2: wave per node, 6 edges per vmem instruction. Lane m reads uint2 =
// {g0-quad fp8, d-quad fp8} for outputs 4m..4m+3; msg = g0 + p*d in pk-f32.
// ---------------------------------------------------------------------------
__global__ __launch_bounds__(256) void k_agg2f(
    const unsigned* __restrict__ hwq, const float* __restrict__ rt,
    const unsigned* __restrict__ pay, const int* __restrict__ offs,
    const int* __restrict__ cnt, float* __restrict__ out)
{
    __shared__ float scr[4][OUTC];
    int t = threadIdx.x;
    int w = t >> 6, lane = t & 63;
    int slot = lane / 10;            // 0..5 active, 6 = lanes 60-63 (zero row)
    int m = lane - slot * 10;        // 0..9 -> outputs 4m..4m+3

    for (int n0 = blockIdx.x * 4; n0 < NN; n0 += gridDim.x * 4) {
        int n = n0 + w;
        int e0 = offs[n], c = cnt[n];

        v2f a01 = {0.f, 0.f}, a23 = {0.f, 0.f};
        for (int base = 0; base < c; base += 64) {
            int bc = min(c - base, 64);
            int li = (lane < bc) ? lane : (bc - 1);
            unsigned pl = pay[e0 + base + li];
            for (int g = 0; g < bc; g += 6) {
                int je = g + slot;
                unsigned v = (unsigned)__shfl((int)pl, je & 63);
                bool valid = (slot < 6) && (je < bc);
                int sj = valid ? pdec_s(v) : NN;        // invalid -> zero row
                float pj = pdec_p(v);
                v2f pp = {pj, pj};
                uint2 gv = *((const uint2*)(hwq + (size_t)sj * 20) + m);
                v2f g01 = __builtin_amdgcn_cvt_pk_f32_fp8(gv.x, false);
                v2f g23 = __builtin_amdgcn_cvt_pk_f32_fp8(gv.x, true);
                v2f d01 = __builtin_amdgcn_cvt_pk_f32_fp8(gv.y, false);
                v2f d23 = __builtin_amdgcn_cvt_pk_f32_fp8(gv.y, true);
                a01 += __builtin_elementwise_fma(pp, d01, g01);
                a23 += __builtin_elementwise_fma(pp, d23, g23);
            }
        }

        // fold 6 slots: +30, then +10 and +20
        a01.x += __shfl(a01.x, (lane + 30) & 63);
        a01.y += __shfl(a01.y, (lane + 30) & 63);
        a23.x += __shfl(a23.x, (lane + 30) & 63);
        a23.y += __shfl(a23.y, (lane + 30) & 63);
        {
            float u0 = a01.x, u1 = a01.y, u2 = a23.x, u3 = a23.y;
            a01.x += __shfl(u0, (lane + 10) & 63) + __shfl(u0, (lane + 20) & 63);
            a01.y += __shfl(u1, (lane + 10) & 63) + __shfl(u1, (lane + 20) & 63);
            a23.x += __shfl(u2, (lane + 10) & 63) + __shfl(u2, (lane + 20) & 63);
            a23.y += __shfl(u3, (lane + 10) & 63) + __shfl(u3, (lane + 20) & 63);
        }

        asm volatile("" ::: "memory");
        if (lane < 10) {
            scr[w][4 * m]     = a01.x;
            scr[w][4 * m + 1] = a01.y;
            scr[w][4 * m + 2] = a23.x;
            scr[w][4 * m + 3] = a23.y;
        }
        asm volatile("" ::: "memory");

        float inv = 1.0f / fmaxf((float)c, 1.0f);
        float r = 0.0f;
        if (lane < OUTC)
            r = fmaf(scr[w][lane], inv, rt[(size_t)n * OUTC + lane]);

        float mx = (lane < OUTC) ? r : -1e30f;
#pragma unroll
        for (int off = 32; off > 0; off >>= 1) mx = fmaxf(mx, __shfl_xor(mx, off));
        float ex = (lane < OUTC) ? expf(r - mx) : 0.0f;
#pragma unroll
        for (int off = 32; off > 0; off >>= 1) ex += __shfl_xor(ex, off);
        float lse = mx + logf(ex);

        if (lane < OUTC) out[(size_t)n * OUTC + lane] = r - lse;
    }
}

// ---------------------------------------------------------------------------
extern "C" void kernel_launch(void* const* d_in, const int* in_sizes, int n_in,
                              void* d_out, int out_size, void* d_ws, size_t ws_size,
                              hipStream_t stream)
{
    const float* x     = (const float*)d_in[0];
    const int*   ei    = (const int*)  d_in[1];
    const float* ea    = (const float*)d_in[2];
    const float* W1    = (const float*)d_in[3];
    const float* root1 = (const float*)d_in[4];
    const float* b1    = (const float*)d_in[5];
    const float* W2    = (const float*)d_in[6];
    const float* root2 = (const float*)d_in[7];
    const float* b2    = (const float*)d_in[8];
    float* out = (float*)d_out;

    const int* src = ei;
    const int* dst = ei + NE;

    // workspace layout (~70 MB)
    char* wsp = (char*)d_ws;
    int*  cnt   = (int*)wsp;  wsp += sizeof(int) * NN;
    int*  offs  = (int*)wsp;  wsp += sizeof(int) * NN;
    int*  gcur  = (int*)wsp;  wsp += sizeof(int) * 512;
    int*  bbase = (int*)wsp;  wsp += sizeof(int) * 512;
    unsigned* pay = (unsigned*)wsp; wsp += sizeof(unsigned) * NE;                     // 6.4 MB
    unsigned* xq  = (unsigned*)wsp; wsp += sizeof(unsigned) * (size_t)(NN + 1) * 8;   // 3.2 MB
    ushort* Apre  = (ushort*)wsp; wsp += sizeof(ushort) * (size_t)NN * 96;            // 19.2 MB
    unsigned* hwq = (unsigned*)wsp; wsp += sizeof(unsigned) * (size_t)(NN + 1) * 20;  // 8 MB
    float* rt     = (float*)wsp; wsp += sizeof(float) * (size_t)NN * OUTC;            // 16 MB
    ushort* W1T   = (ushort*)wsp; wsp += sizeof(ushort) * 64 * 96;
    ushort* W2T   = (ushort*)wsp; wsp += sizeof(ushort) * 128 * 64;
    wsp = (char*)(((size_t)wsp + 15) & ~(size_t)15);
    uint2* slab   = (uint2*)wsp; wsp += sizeof(uint2) * (size_t)NBUCK * BCAP;         // 16 MB

    hipMemsetAsync(gcur, 0, sizeof(int) * 512, stream);
    hipMemsetAsync(hwq + (size_t)NN * 20, 0, 80, stream);   // zero row

    k_xq    <<<((NN + 1) * 8 + 255) / 256, 256, 0, stream>>>(x, xq);
    k_wprep <<<(64 * 96 + 128 * 64 + 255) / 256, 256, 0, stream>>>(W1, root1, W2, root2, W1T, W2T);
    k_bin   <<<(NE + 4095) / 4096, 256, 0, stream>>>(src, dst, ea, gcur, slab);
    k_bscan <<<1, 512, 0, stream>>>(gcur, bbase);
    k_csr   <<<NBUCK, 256, 0, stream>>>(slab, gcur, bbase, cnt, offs, pay);

    k_agg1  <<<2048, 256, 0, stream>>>(xq, pay, offs, cnt, x, Apre);
    k_node_mfma<<<(NN + 63) / 64, 256, 0, stream>>>(Apre, W1T, W2T, b1, b2, hwq, rt);
    k_agg2f <<<2048, 256, 0, stream>>>(hwq, rt, pay, offs, cnt, out);
}